// Round 1
// baseline (501.397 us; speedup 1.0000x reference)
//
#include <hip/hip_runtime.h>
#include <hip/hip_bf16.h>

// ModulatedConv2D: B=8, CIN=COUT=32, H=W=512, K=3, LATENT=512
// Strategy: kernel A computes per-batch modulated bf16 weights in MFMA
// A-fragment layout; kernel B does implicit-GEMM conv with
// mfma_f32_32x32x16_bf16 (M=cout, N=32 pixels along w, K=tap*32+cin).

typedef __bf16  bf16x8_t  __attribute__((ext_vector_type(8)));
typedef float   f32x16_t  __attribute__((ext_vector_type(16)));

#define CIN    32
#define COUT   32
#define IMH    512
#define IMW    512
#define HWSZ   (512*512)
#define LATENTD 512
#define NTAP   9

// conv tile geometry
#define TH 16
#define TW 32
#define TROWS (TH+2)          // 18
#define TCOLS (TW+2)          // 34
#define ROWE  (TCOLS*32)      // 1088 bf16 elements per LDS row
// LDS: 18*1088*2 = 39168 B -> 4 workgroups/CU possible

// ---------------- kernel A: style + demod + bf16 weight fragments ----------
// wsA layout: wsA[b*9216 + (tap*2 + c0h)*512 + lane*8 + j]
//   = bf16( rc * w[tap][c][cout] * s[b][c] * d[b][cout] )
//   with c = c0h*16 + (lane>>5)*8 + j, cout = lane&31
// -> exactly the A-operand fragment of mfma_f32_32x32x16_bf16 for K-step
//    (tap, c0h): A[m=lane&31][k=8*(lane>>5)+j].
__global__ __launch_bounds__(256) void modw_kernel(
    const float* __restrict__ y, const float* __restrict__ w,
    const float* __restrict__ wd, const float* __restrict__ bd,
    __bf16* __restrict__ wsA)
{
  const int b = blockIdx.x;
  const int t = threadIdx.x;
  const int c = t & 31, part = t >> 5;
  const float rc = 0.05892556509887896f;   // 1/sqrt(3*3*32)
  const float dc = 0.04419417382415922f;   // 1/sqrt(512)
  __shared__ float red[8][32];
  __shared__ float s_sh[32];
  __shared__ float d_sh[32];

  // s[c] = sum_l y[b][l] * wd[l][c] * dc + bd[c] + 1
  float accv = 0.f;
  const float* yb = y + b * LATENTD;
  for (int l = part * 64; l < part * 64 + 64; ++l)
    accv += yb[l] * wd[l * 32 + c];
  red[part][c] = accv;
  __syncthreads();
  if (t < 32) {
    float v = 0.f;
#pragma unroll
    for (int p = 0; p < 8; ++p) v += red[p][t];
    s_sh[t] = v * dc + bd[t] + 1.0f;
  }
  __syncthreads();

  // d[cout] = rsqrt( sum_{tap,cin} (rc*w*s)^2 + 1e-8 )
  float ss = 0.f;
  for (int i = part * 36; i < part * 36 + 36; ++i) {
    int tap = i >> 5, ci = i & 31;
    float v = rc * w[(tap * 32 + ci) * 32 + c] * s_sh[ci];
    ss += v * v;
  }
  red[part][c] = ss;
  __syncthreads();
  if (t < 32) {
    float v = 0.f;
#pragma unroll
    for (int p = 0; p < 8; ++p) v += red[p][t];
    d_sh[t] = rsqrtf(v + 1e-8f);
  }
  __syncthreads();

  // write fragments
  for (int e = t; e < NTAP * 1024; e += 256) {
    int j   = e & 7;
    int l   = (e >> 3) & 63;
    int c0h = (e >> 9) & 1;
    int tap = e >> 10;
    int cc  = c0h * 16 + ((l >> 5) << 3) + j;
    int co  = l & 31;
    float v = rc * w[(tap * 32 + cc) * 32 + co] * s_sh[cc] * d_sh[co];
    wsA[b * 9216 + e] = (__bf16)v;
  }
}

// ---------------- kernel B: implicit-GEMM conv -----------------------------
// One workgroup = one (b, 16x32 spatial tile). 4 waves; wave wv computes
// output rows wv*4..wv*4+3, each as one 32(cout) x 32(pixels) MFMA tile.
// x tile staged in LDS as HWC bf16 with a 16B-block XOR swizzle so that the
// per-K-step B-fragment ds_read_b128 (32 w-consecutive lanes x 2 c-blocks)
// spreads evenly over all 8 16B slots of the 128B bank rows.
__global__ __launch_bounds__(256) void conv_kernel(
    const float* __restrict__ x, const __bf16* __restrict__ wsA,
    float* __restrict__ out)
{
  __shared__ __align__(16) __bf16 xt[TROWS * ROWE];

  const int wt = blockIdx.x, ht = blockIdx.y, b = blockIdx.z;
  const int h0 = ht * TH, w0 = wt * TW;
  const int t = threadIdx.x;
  const int lane = t & 63, wv = t >> 6;

  // A fragments: 18 K-steps (9 taps x 2 channel halves), reused by all tiles
  bf16x8_t af[18];
  {
    const __bf16* wb = wsA + b * 9216 + lane * 8;
#pragma unroll
    for (int i = 0; i < 18; ++i)
      af[i] = *(const bf16x8_t*)(wb + i * 512);
  }

  // stage x tile: global NCHW f32 -> LDS HWC bf16 (zero-fill SAME padding)
  const float* xb = x + (size_t)b * CIN * HWSZ;
  for (int i = t; i < 4 * TROWS * TCOLS; i += 256) {
    int cb  = i / (TROWS * TCOLS);
    int rem = i - cb * (TROWS * TCOLS);
    int hi  = rem / TCOLS;
    int wi  = rem - hi * TCOLS;
    int gh = h0 + hi - 1, gw = w0 + wi - 1;
    bf16x8_t bv;
    if ((unsigned)gh < (unsigned)IMH && (unsigned)gw < (unsigned)IMW) {
      const float* p = xb + (size_t)(cb * 8) * HWSZ + gh * IMW + gw;
#pragma unroll
      for (int j = 0; j < 8; ++j) bv[j] = (__bf16)p[(size_t)j * HWSZ];
    } else {
#pragma unroll
      for (int j = 0; j < 8; ++j) bv[j] = (__bf16)0.f;
    }
    int off = hi * ROWE + wi * 32 + ((cb * 8) ^ ((wi & 3) << 3));
    *(bf16x8_t*)&xt[off] = bv;
  }
  __syncthreads();

  const int n = lane & 31, hb = lane >> 5;
  float* ob = out + (size_t)b * COUT * HWSZ + (size_t)h0 * IMW + w0;

  for (int r = 0; r < 4; ++r) {
    const int hi = wv * 4 + r;           // output row within tile, 0..15
    f32x16_t acc = {};
#pragma unroll
    for (int tap = 0; tap < NTAP; ++tap) {
      const int kh = tap / 3, kw = tap - kh * 3;
      const int row = hi + kh;           // LDS row (input h = h0+hi+kh-1)
      const int wi  = kw + n;            // LDS col (input w = w0+n+kw-1)
#pragma unroll
      for (int c0h = 0; c0h < 2; ++c0h) {
        const int cb  = c0h * 2 + hb;    // 8-channel block for this lane
        const int off = row * ROWE + wi * 32 + ((cb * 8) ^ ((wi & 3) << 3));
        bf16x8_t bf = *(const bf16x8_t*)&xt[off];
        acc = __builtin_amdgcn_mfma_f32_32x32x16_bf16(
            af[tap * 2 + c0h], bf, acc, 0, 0, 0);
      }
    }
    // C/D layout (HW-verified): col = lane&31 (pixel), row = cout =
    // (reg&3) + 8*(reg>>2) + 4*(lane>>5)
    float* orow = ob + (size_t)hi * IMW;
#pragma unroll
    for (int r2 = 0; r2 < 16; ++r2) {
      int co = (r2 & 3) + ((r2 >> 2) << 3) + (hb << 2);
      orow[(size_t)co * HWSZ + n] = acc[r2];
    }
  }
}

extern "C" void kernel_launch(void* const* d_in, const int* in_sizes, int n_in,
                              void* d_out, int out_size, void* d_ws, size_t ws_size,
                              hipStream_t stream) {
  const float* x  = (const float*)d_in[0];   // [8,32,512,512]
  const float* y  = (const float*)d_in[1];   // [8,512]
  const float* w  = (const float*)d_in[2];   // [3,3,32,32]
  const float* wd = (const float*)d_in[3];   // [512,32]
  const float* bd = (const float*)d_in[4];   // [32]
  float* o = (float*)d_out;                  // [8,32,512,512]
  __bf16* wsA = (__bf16*)d_ws;               // 8*9216 bf16 = 147456 B

  modw_kernel<<<dim3(8), dim3(256), 0, stream>>>(y, w, wd, bd, wsA);
  dim3 grid(IMW / TW, IMH / TH, 8);          // (16, 32, 8)
  conv_kernel<<<grid, dim3(256), 0, stream>>>(x, wsA, o);
}

// Round 2
// 494.601 us; speedup vs baseline: 1.0137x; 1.0137x over previous
//
#include <hip/hip_runtime.h>
#include <hip/hip_bf16.h>

// ModulatedConv2D: B=8, CIN=COUT=32, H=W=512, K=3, LATENT=512
// kernel A: per-batch modulated bf16 weights in MFMA A-fragment layout.
// kernel B: implicit-GEMM conv, mfma_f32_32x32x16_bf16
//           (M=cout, N=32 pixels along w, K=tap*32+cin).
// R2: TH=8 -> 8192 WGs, 7 blocks/CU (occupancy fix); conflict-free
//     channel-plane LDS layout; bijective XCD swizzle (1 batch per XCD).

typedef __bf16  bf16x8_t  __attribute__((ext_vector_type(8)));
typedef float   f32x16_t  __attribute__((ext_vector_type(16)));

#define CIN    32
#define COUT   32
#define IMH    512
#define IMW    512
#define HWSZ   (512*512)
#define LATENTD 512
#define NTAP   9

// conv tile geometry
#define TH 8
#define TW 32
#define TROWS (TH+2)          // 10
#define TCOLS (TW+2)          // 34
// LDS: xt[cb][row][wi][8] bf16 = 4*10*34*8*2 = 21760 B -> 7 blocks/CU

// ---------------- kernel A: style + demod + bf16 weight fragments ----------
// wsA[b*9216 + (tap*2 + c0h)*512 + lane*8 + j]
//   = bf16( rc * w[tap][c][cout] * s[b][c] * d[b][cout] )
//   with c = c0h*16 + (lane>>5)*8 + j, cout = lane&31
// -> A-operand fragment of mfma_f32_32x32x16_bf16 for K-step (tap, c0h).
__global__ __launch_bounds__(256) void modw_kernel(
    const float* __restrict__ y, const float* __restrict__ w,
    const float* __restrict__ wd, const float* __restrict__ bd,
    __bf16* __restrict__ wsA)
{
  const int b = blockIdx.x;
  const int t = threadIdx.x;
  const int c = t & 31, part = t >> 5;
  const float rc = 0.05892556509887896f;   // 1/sqrt(3*3*32)
  const float dc = 0.04419417382415922f;   // 1/sqrt(512)
  __shared__ float red[8][32];
  __shared__ float s_sh[32];
  __shared__ float d_sh[32];

  // s[c] = sum_l y[b][l] * wd[l][c] * dc + bd[c] + 1
  float accv = 0.f;
  const float* yb = y + b * LATENTD;
  for (int l = part * 64; l < part * 64 + 64; ++l)
    accv += yb[l] * wd[l * 32 + c];
  red[part][c] = accv;
  __syncthreads();
  if (t < 32) {
    float v = 0.f;
#pragma unroll
    for (int p = 0; p < 8; ++p) v += red[p][t];
    s_sh[t] = v * dc + bd[t] + 1.0f;
  }
  __syncthreads();

  // d[cout] = rsqrt( sum_{tap,cin} (rc*w*s)^2 + 1e-8 )
  float ss = 0.f;
  for (int i = part * 36; i < part * 36 + 36; ++i) {
    int tap = i >> 5, ci = i & 31;
    float v = rc * w[(tap * 32 + ci) * 32 + c] * s_sh[ci];
    ss += v * v;
  }
  red[part][c] = ss;
  __syncthreads();
  if (t < 32) {
    float v = 0.f;
#pragma unroll
    for (int p = 0; p < 8; ++p) v += red[p][t];
    d_sh[t] = rsqrtf(v + 1e-8f);
  }
  __syncthreads();

  // write fragments
  for (int e = t; e < NTAP * 1024; e += 256) {
    int j   = e & 7;
    int l   = (e >> 3) & 63;
    int c0h = (e >> 9) & 1;
    int tap = e >> 10;
    int cc  = c0h * 16 + ((l >> 5) << 3) + j;
    int co  = l & 31;
    float v = rc * w[(tap * 32 + cc) * 32 + co] * s_sh[cc] * d_sh[co];
    wsA[b * 9216 + e] = (__bf16)v;
  }
}

// ---------------- kernel B: implicit-GEMM conv -----------------------------
// One workgroup = one (b, 8x32 spatial tile). 4 waves; wave wv computes
// output rows wv*2..wv*2+1, each as one 32(cout) x 32(pixels) MFMA tile.
// LDS layout xt[cb][row][wi][8]: channel-plane, so both the staging
// ds_write_b128 and the per-K-step B-fragment ds_read_b128 are
// lane-sequential 16B strides -> conflict-free.
__global__ __launch_bounds__(256) void conv_kernel(
    const float* __restrict__ x, const __bf16* __restrict__ wsA,
    float* __restrict__ out)
{
  __shared__ __align__(16) __bf16 xt[4 * TROWS * TCOLS * 8];

  // bijective XCD swizzle: 8192 WGs, 1024 per XCD -> one batch per XCD
  const int bid = blockIdx.x;
  const int swz = (bid & 7) * 1024 + (bid >> 3);
  const int wt = swz & 15, ht = (swz >> 4) & 63, b = swz >> 10;

  const int h0 = ht * TH, w0 = wt * TW;
  const int t = threadIdx.x;
  const int lane = t & 63, wv = t >> 6;

  // A fragments: 18 K-steps (9 taps x 2 channel halves)
  bf16x8_t af[18];
  {
    const __bf16* wb = wsA + b * 9216 + lane * 8;
#pragma unroll
    for (int i = 0; i < 18; ++i)
      af[i] = *(const bf16x8_t*)(wb + i * 512);
  }

  // stage x tile: global NCHW f32 -> LDS channel-plane bf16 (SAME padding)
  const float* xb = x + (size_t)b * CIN * HWSZ;
  for (int i = t; i < 4 * TROWS * TCOLS; i += 256) {
    int cb  = i / (TROWS * TCOLS);
    int rem = i - cb * (TROWS * TCOLS);
    int hi  = rem / TCOLS;
    int wi  = rem - hi * TCOLS;
    int gh = h0 + hi - 1, gw = w0 + wi - 1;
    bf16x8_t bv;
    if ((unsigned)gh < (unsigned)IMH && (unsigned)gw < (unsigned)IMW) {
      const float* p = xb + (size_t)(cb * 8) * HWSZ + gh * IMW + gw;
#pragma unroll
      for (int j = 0; j < 8; ++j) bv[j] = (__bf16)p[(size_t)j * HWSZ];
    } else {
#pragma unroll
      for (int j = 0; j < 8; ++j) bv[j] = (__bf16)0.f;
    }
    *(bf16x8_t*)&xt[(size_t)i * 8] = bv;   // i == (cb*TROWS + hi)*TCOLS + wi
  }
  __syncthreads();

  const int n = lane & 31, hb = lane >> 5;
  float* ob = out + (size_t)b * COUT * HWSZ + (size_t)h0 * IMW + w0;

  for (int r = 0; r < 2; ++r) {
    const int hi = wv * 2 + r;           // output row within tile, 0..7
    f32x16_t acc = {};
#pragma unroll
    for (int tap = 0; tap < NTAP; ++tap) {
      const int kh = tap / 3, kw = tap - kh * 3;
      const int row = hi + kh;           // LDS row (input h = h0+hi+kh-1)
      const int wi  = kw + n;            // LDS col (input w = w0+n+kw-1)
#pragma unroll
      for (int c0h = 0; c0h < 2; ++c0h) {
        const int cb  = c0h * 2 + hb;    // 8-channel block for this lane
        const int off = ((cb * TROWS + row) * TCOLS + wi) * 8;
        bf16x8_t bf = *(const bf16x8_t*)&xt[off];
        acc = __builtin_amdgcn_mfma_f32_32x32x16_bf16(
            af[tap * 2 + c0h], bf, acc, 0, 0, 0);
      }
    }
    // C/D layout: col = lane&31 (pixel), cout = (reg&3)+8*(reg>>2)+4*(lane>>5)
    float* orow = ob + (size_t)hi * IMW;
#pragma unroll
    for (int r2 = 0; r2 < 16; ++r2) {
      int co = (r2 & 3) + ((r2 >> 2) << 3) + (hb << 2);
      orow[(size_t)co * HWSZ + n] = acc[r2];
    }
  }
}

extern "C" void kernel_launch(void* const* d_in, const int* in_sizes, int n_in,
                              void* d_out, int out_size, void* d_ws, size_t ws_size,
                              hipStream_t stream) {
  const float* x  = (const float*)d_in[0];   // [8,32,512,512]
  const float* y  = (const float*)d_in[1];   // [8,512]
  const float* w  = (const float*)d_in[2];   // [3,3,32,32]
  const float* wd = (const float*)d_in[3];   // [512,32]
  const float* bd = (const float*)d_in[4];   // [32]
  float* o = (float*)d_out;                  // [8,32,512,512]
  __bf16* wsA = (__bf16*)d_ws;               // 8*9216 bf16 = 147456 B

  modw_kernel<<<dim3(8), dim3(256), 0, stream>>>(y, w, wd, bd, wsA);
  conv_kernel<<<dim3(8192), dim3(256), 0, stream>>>(x, wsA, o);
}